// Round 9
// baseline (520.473 us; speedup 1.0000x reference)
//
#include <hip/hip_runtime.h>

constexpr float BN_EPS = 1e-5f;
#define BSH 7          // bucket shift: 128 nodes per bucket
#define NBMAX 1024     // supports n <= 131072

typedef __attribute__((ext_vector_type(8))) short bf16x8;
typedef __attribute__((ext_vector_type(4))) float f32x4;

// bf16 helpers (bit ops; RNE on pack)
__device__ inline float2 bf2x2(unsigned int v) {
    union { unsigned int i; float f; } a, b;
    a.i = v << 16;
    b.i = v & 0xFFFF0000u;
    return make_float2(a.f, b.f);
}
__device__ inline float bf2f(unsigned short u) {
    union { unsigned int i; float f; } a;
    a.i = ((unsigned int)u) << 16;
    return a.f;
}
__device__ inline unsigned short f2bf(float f) {
    union { float f; unsigned int i; } c;
    c.f = f;
    unsigned int i = c.i;
    return (unsigned short)((i + 0x7FFFu + ((i >> 16) & 1u)) >> 16);
}

// swizzled ushort index into a [rows][128] bf16 LDS tile: 16B slot XOR'd by row&7
__device__ inline int wsw(int row, int k) {
    return row * 128 + ((((k >> 3) ^ (row & 7)) << 3) | (k & 7));
}

// ---------------- zero bucket counters ----------------
__global__ void k_zero(int* __restrict__ gcount) {
    gcount[threadIdx.x] = 0;  // 1024 threads
}

// ---------------- phase A1: bucket histogram (LDS-privatized) ----------------
__global__ __launch_bounds__(256) void k_hist(const int* __restrict__ dst, int* __restrict__ gcount,
                                              int E, int NB) {
    __shared__ int lh[NBMAX];
    const int tid = threadIdx.x;
    for (int i = tid; i < NBMAX; i += 256) lh[i] = 0;
    __syncthreads();
    const int base = blockIdx.x * 8192;
#pragma unroll
    for (int i = 0; i < 32; ++i) {
        int e = base + i * 256 + tid;
        if (e < E) atomicAdd(&lh[dst[e] >> BSH], 1);
    }
    __syncthreads();
    for (int b = tid; b < NB; b += 256) {
        int c = lh[b];
        if (c) atomicAdd(&gcount[b], c);
    }
}

// ---------------- phase A2: scan bucket counts; init cursors; zero BN stats ----------------
__global__ __launch_bounds__(1024) void k_scanb(const int* __restrict__ gcount, int* __restrict__ gstart,
                                                int* __restrict__ cursor, float* __restrict__ stats, int NB) {
    __shared__ int tmp[1024];
    const int t = threadIdx.x;
    int v = (t < NB) ? gcount[t] : 0;
    tmp[t] = v;
    __syncthreads();
    for (int off = 1; off < 1024; off <<= 1) {
        int u = (t >= off) ? tmp[t - off] : 0;
        __syncthreads();
        tmp[t] += u;
        __syncthreads();
    }
    if (t < NB) { int ex = tmp[t] - v; gstart[t] = ex; cursor[t] = ex; }
    if (t == NB - 1) gstart[NB] = tmp[t];
    if (t < 512) stats[t] = 0.f;
}

// ---------------- phase A3: scatter edges into bucket-grouped pairs (LDS reorder) ----------------
__global__ __launch_bounds__(256) void k_scatter(const int* __restrict__ src, const int* __restrict__ dst,
                                                 int* __restrict__ cursor, int2* __restrict__ pairs,
                                                 int E, int NB) {
    __shared__ int lh[NBMAX], lbase[NBMAX], gbase[NBMAX], lcur[NBMAX];
    __shared__ int2 buf[4096];
    __shared__ unsigned short bo[4096];
    const int tid = threadIdx.x;
    for (int i = tid; i < NBMAX; i += 256) lh[i] = 0;
    __syncthreads();
    const int base = blockIdx.x * 4096;
    const int cnt = min(4096, E - base);
#pragma unroll
    for (int i = 0; i < 16; ++i) {
        int e = base + i * 256 + tid;
        if (e < E) atomicAdd(&lh[dst[e] >> BSH], 1);
    }
    __syncthreads();
    int s0 = lh[tid * 4], s1 = lh[tid * 4 + 1], s2 = lh[tid * 4 + 2], s3 = lh[tid * 4 + 3];
    int ts = s0 + s1 + s2 + s3;
    lcur[tid] = ts;
    __syncthreads();
    for (int off = 1; off < 256; off <<= 1) {
        int u = (tid >= off) ? lcur[tid - off] : 0;
        __syncthreads();
        lcur[tid] += u;
        __syncthreads();
    }
    int ex = lcur[tid] - ts;
    lbase[tid * 4] = ex;
    lbase[tid * 4 + 1] = ex + s0;
    lbase[tid * 4 + 2] = ex + s0 + s1;
    lbase[tid * 4 + 3] = ex + s0 + s1 + s2;
    __syncthreads();
    for (int b = tid; b < NB; b += 256) {
        int c = lh[b];
        gbase[b] = c ? atomicAdd(&cursor[b], c) : 0;
    }
    for (int i = tid; i < NBMAX; i += 256) lcur[i] = 0;
    __syncthreads();
#pragma unroll
    for (int i = 0; i < 16; ++i) {
        int e = base + i * 256 + tid;
        if (e < E) {
            int d = dst[e];
            int b = d >> BSH;
            int p = lbase[b] + atomicAdd(&lcur[b], 1);
            buf[p] = make_int2(src[e], d);
            bo[p] = (unsigned short)b;
        }
    }
    __syncthreads();
#pragma unroll
    for (int i = 0; i < 16; ++i) {
        int p = i * 256 + tid;
        if (p < cnt) {
            int b = bo[p];
            pairs[gbase[b] + (p - lbase[b])] = buf[p];
        }
    }
}

// ---------------- phase B: per-bucket fine sort -> rowptr/rowend/dinv/esrc ----------------
__global__ __launch_bounds__(256) void k_build(const int2* __restrict__ pairs, const int* __restrict__ gstart,
                                               int* __restrict__ rowptr, int* __restrict__ rowend,
                                               float* __restrict__ dinv, int* __restrict__ esrc, int n) {
    __shared__ int lh[128], lsc[128], lcur[128];
    const int tid = threadIdx.x;
    const int b = blockIdx.x;
    const int e0 = gstart[b], e1 = gstart[b + 1];
    const int node0 = b << BSH;
    if (tid < 128) lh[tid] = 0;
    __syncthreads();
    for (int e = e0 + tid; e < e1; e += 256) atomicAdd(&lh[pairs[e].y - node0], 1);
    __syncthreads();
    int v = (tid < 128) ? lh[tid] : 0;
    if (tid < 128) lsc[tid] = v;
    __syncthreads();
    for (int off = 1; off < 128; off <<= 1) {
        int u = (tid >= off && tid < 128) ? lsc[tid - off] : 0;
        __syncthreads();
        if (tid < 128) lsc[tid] += u;
        __syncthreads();
    }
    if (tid < 128) {
        int ex = lsc[tid] - v;
        lcur[tid] = ex;
        int node = node0 + tid;
        if (node < n) {
            int rp = e0 + ex;
            rowptr[node] = rp;
            rowend[node] = rp + v;
            dinv[node] = rsqrtf((float)(v + 1));  // +1 self loop
        }
    }
    __syncthreads();
    for (int e = e0 + tid; e < e1; e += 256) {
        int2 p = pairs[e];
        int pos = atomicAdd(&lcur[p.y - node0], 1);
        esrc[e0 + pos] = p.x;
    }
}

// ---------------- GEMM1 (MFMA): g1 = bf16( dinv ⊙ (x @ W1^T) ) ----------------
__global__ __launch_bounds__(256) void k_gemm1(const float* __restrict__ x,
                                               const float* __restrict__ W1,
                                               const float* __restrict__ dinv,
                                               unsigned short* __restrict__ g1, int n) {
    __shared__ unsigned short Ws[128 * 128];
    const int tid = threadIdx.x;
#pragma unroll
    for (int i = 0; i < 16; ++i) {
        int idx4 = i * 256 + tid;
        int j = idx4 >> 5;
        int k = (idx4 & 31) * 4;
        float4 v = *(const float4*)&W1[(size_t)j * 128 + k];
        ushort4 u;
        u.x = f2bf(v.x); u.y = f2bf(v.y); u.z = f2bf(v.z); u.w = f2bf(v.w);
        *(ushort2*)&Ws[wsw(j, k)] = make_ushort2(u.x, u.y);
        *(ushort2*)&Ws[wsw(j, k + 2)] = make_ushort2(u.z, u.w);
    }
    __syncthreads();
    const int wave = tid >> 6, l = tid & 63;
    const int am = l & 15;
    const int kg = l >> 4;
    const int row0 = blockIdx.x * 64 + wave * 16;
    const int grow = row0 + am;
    const float* xrow = &x[(size_t)(grow < n ? grow : 0) * 128];
    f32x4 acc[8] = {};
#pragma unroll
    for (int k0 = 0; k0 < 128; k0 += 32) {
        const int kk = k0 + kg * 8;
        float4 a0 = *(const float4*)&xrow[kk];
        float4 a1 = *(const float4*)&xrow[kk + 4];
        union { unsigned short u[8]; bf16x8 v; } af;
        af.u[0] = f2bf(a0.x); af.u[1] = f2bf(a0.y); af.u[2] = f2bf(a0.z); af.u[3] = f2bf(a0.w);
        af.u[4] = f2bf(a1.x); af.u[5] = f2bf(a1.y); af.u[6] = f2bf(a1.z); af.u[7] = f2bf(a1.w);
#pragma unroll
        for (int ct = 0; ct < 8; ++ct) {
            union { uint4 q; bf16x8 v; } bf;
            bf.q = *(const uint4*)&Ws[wsw(ct * 16 + am, kk)];
            acc[ct] = __builtin_amdgcn_mfma_f32_16x16x32_bf16(af.v, bf.v, acc[ct], 0, 0, 0);
        }
    }
#pragma unroll
    for (int r = 0; r < 4; ++r) {
        int orow = row0 + kg * 4 + r;
        if (orow < n) {
            float di = dinv[orow];
#pragma unroll
            for (int ct = 0; ct < 8; ++ct)
                g1[(size_t)orow * 128 + ct * 16 + am] = f2bf(acc[ct][r] * di);
        }
    }
}

// ---------------- pull1 (XCD feature-sliced): slice = blockIdx&7 handles feats [slice*16, slice*16+16) ----------------
// wave = node; lanes: eslot = lane>>3 (8 edges in parallel), fl = lane&7 (2 feats each)
__global__ __launch_bounds__(256) void k_pull1(const int* __restrict__ rowptr, const int* __restrict__ rowend,
                                               const int* __restrict__ esrc, const unsigned short* __restrict__ g,
                                               const float* __restrict__ dinv, const float* __restrict__ b1,
                                               unsigned short* __restrict__ h1, float* __restrict__ stats, int n) {
    __shared__ float2 sS[4][8], sQ[4][8];
    const int tid = threadIdx.x;
    const int slice = blockIdx.x & 7;
    const int wid = tid >> 6;
    const int lane = tid & 63;
    const int eslot = lane >> 3;
    const int fl = lane & 7;
    const int fbase = slice * 16 + fl * 2;
    const int wv = (blockIdx.x >> 3) * 4 + wid;
    const int nwv = (gridDim.x >> 3) * 4;
    const float2 bias = *(const float2*)&b1[fbase];
    float2 psum = {0.f, 0.f}, psq = {0.f, 0.f};
    for (int node = wv; node < n; node += nwv) {
        const int b = rowptr[node], e = rowend[node];
        float2 a0 = {0.f, 0.f}, a1 = {0.f, 0.f};
        {   // self loop (eslot 0 only)
            float2 s2 = bf2x2(*(const unsigned int*)&g[(size_t)node * 128 + fbase]);
            if (eslot == 0) { a0.x += s2.x; a0.y += s2.y; }
        }
        int j = b;
        for (; j + 16 <= e; j += 16) {
            int s0 = esrc[j + eslot];
            int s1 = esrc[j + 8 + eslot];
            unsigned int v0 = *(const unsigned int*)&g[(size_t)s0 * 128 + fbase];
            unsigned int v1 = *(const unsigned int*)&g[(size_t)s1 * 128 + fbase];
            float2 f0 = bf2x2(v0), f1 = bf2x2(v1);
            a0.x += f0.x; a0.y += f0.y;
            a1.x += f1.x; a1.y += f1.y;
        }
        if (j < e) {  // masked tail (up to 15 edges)
            int i0 = j + eslot;
            bool vv0 = i0 < e;
            int s0 = vv0 ? esrc[i0] : node;
            float2 f0 = bf2x2(*(const unsigned int*)&g[(size_t)s0 * 128 + fbase]);
            if (vv0) { a0.x += f0.x; a0.y += f0.y; }
            int i1 = j + 8 + eslot;
            bool vv1 = i1 < e;
            int s1 = vv1 ? esrc[i1] : node;
            float2 f1 = bf2x2(*(const unsigned int*)&g[(size_t)s1 * 128 + fbase]);
            if (vv1) { a1.x += f1.x; a1.y += f1.y; }
        }
        float2 acc = {a0.x + a1.x, a0.y + a1.y};
        acc.x += __shfl_xor(acc.x, 8);  acc.y += __shfl_xor(acc.y, 8);
        acc.x += __shfl_xor(acc.x, 16); acc.y += __shfl_xor(acc.y, 16);
        acc.x += __shfl_xor(acc.x, 32); acc.y += __shfl_xor(acc.y, 32);
        if (eslot == 0) {
            const float di = dinv[node];
            float2 hv = {fmaf(acc.x, di, bias.x), fmaf(acc.y, di, bias.y)};
            unsigned int pk = ((unsigned int)f2bf(hv.y) << 16) | (unsigned int)f2bf(hv.x);
            *(unsigned int*)&h1[(size_t)node * 128 + fbase] = pk;
            psum.x += hv.x; psum.y += hv.y;
            psq.x = fmaf(hv.x, hv.x, psq.x);
            psq.y = fmaf(hv.y, hv.y, psq.y);
        }
    }
    if (eslot == 0) { sS[wid][fl] = psum; sQ[wid][fl] = psq; }
    __syncthreads();
    if (tid < 8) {
        float2 t = {0.f, 0.f}, q = {0.f, 0.f};
#pragma unroll
        for (int w = 0; w < 4; ++w) {
            t.x += sS[w][tid].x; t.y += sS[w][tid].y;
            q.x += sQ[w][tid].x; q.y += sQ[w][tid].y;
        }
        atomicAdd(&stats[slice * 16 + tid * 2 + 0], t.x);
        atomicAdd(&stats[slice * 16 + tid * 2 + 1], t.y);
        atomicAdd(&stats[128 + slice * 16 + tid * 2 + 0], q.x);
        atomicAdd(&stats[128 + slice * 16 + tid * 2 + 1], q.y);
    }
}

// ---------------- BN scale/shift from sums ----------------
__global__ void k_bnfinal(float* __restrict__ stats, const float* __restrict__ gamma,
                          const float* __restrict__ beta, int n) {
    int f = threadIdx.x;  // 128 threads
    float inv_n = 1.f / (float)n;
    float mean = stats[f] * inv_n;
    float var = stats[128 + f] * inv_n - mean * mean;
    float sc = gamma[f] * rsqrtf(var + BN_EPS);
    stats[256 + f] = sc;
    stats[384 + f] = fmaf(-mean, sc, beta[f]);
}

// ---------------- GEMM2 (MFMA): g2 = bf16( dinv ⊙ (relu(BN(h1)) @ W2^T) ), h1 bf16 ----------------
__global__ __launch_bounds__(256) void k_gemm2(const unsigned short* __restrict__ h1,
                                               const float* __restrict__ W2,
                                               const float* __restrict__ dinv,
                                               const float* __restrict__ stats,
                                               unsigned short* __restrict__ g2, int n) {
    __shared__ unsigned short Ws[64 * 128];
    const int tid = threadIdx.x;
#pragma unroll
    for (int i = 0; i < 8; ++i) {
        int idx4 = i * 256 + tid;
        int j = idx4 >> 5;
        int k = (idx4 & 31) * 4;
        float4 v = *(const float4*)&W2[(size_t)j * 128 + k];
        ushort4 u;
        u.x = f2bf(v.x); u.y = f2bf(v.y); u.z = f2bf(v.z); u.w = f2bf(v.w);
        *(ushort2*)&Ws[wsw(j, k)] = make_ushort2(u.x, u.y);
        *(ushort2*)&Ws[wsw(j, k + 2)] = make_ushort2(u.z, u.w);
    }
    __syncthreads();
    const int wave = tid >> 6, l = tid & 63;
    const int am = l & 15;
    const int kg = l >> 4;
    const int row0 = blockIdx.x * 64 + wave * 16;
    const int grow = row0 + am;
    const unsigned short* hrow = &h1[(size_t)(grow < n ? grow : 0) * 128];
    f32x4 acc[4] = {};
#pragma unroll
    for (int k0 = 0; k0 < 128; k0 += 32) {
        const int kk = k0 + kg * 8;
        uint4 hq = *(const uint4*)&hrow[kk];
        float2 p0 = bf2x2(hq.x), p1 = bf2x2(hq.y), p2 = bf2x2(hq.z), p3 = bf2x2(hq.w);
        float hf[8] = {p0.x, p0.y, p1.x, p1.y, p2.x, p2.y, p3.x, p3.y};
        float4 sc0 = *(const float4*)&stats[256 + kk];
        float4 sc1 = *(const float4*)&stats[256 + kk + 4];
        float4 sh0 = *(const float4*)&stats[384 + kk];
        float4 sh1 = *(const float4*)&stats[384 + kk + 4];
        float scv[8] = {sc0.x, sc0.y, sc0.z, sc0.w, sc1.x, sc1.y, sc1.z, sc1.w};
        float shv[8] = {sh0.x, sh0.y, sh0.z, sh0.w, sh1.x, sh1.y, sh1.z, sh1.w};
        union { unsigned short u[8]; bf16x8 v; } af;
#pragma unroll
        for (int jj = 0; jj < 8; ++jj)
            af.u[jj] = f2bf(fmaxf(fmaf(hf[jj], scv[jj], shv[jj]), 0.f));
#pragma unroll
        for (int ct = 0; ct < 4; ++ct) {
            union { uint4 q; bf16x8 v; } bf;
            bf.q = *(const uint4*)&Ws[wsw(ct * 16 + am, kk)];
            acc[ct] = __builtin_amdgcn_mfma_f32_16x16x32_bf16(af.v, bf.v, acc[ct], 0, 0, 0);
        }
    }
#pragma unroll
    for (int r = 0; r < 4; ++r) {
        int orow = row0 + kg * 4 + r;
        if (orow < n) {
            float di = dinv[orow];
#pragma unroll
            for (int ct = 0; ct < 4; ++ct)
                g2[(size_t)orow * 64 + ct * 16 + am] = f2bf(acc[ct][r] * di);
        }
    }
}

// ---------------- pull2 (XCD feature-sliced): slice = blockIdx&7 handles feats [slice*8, slice*8+8) ----------------
// wave = node; lanes: eslot = lane>>2 (16 edges in parallel), fl = lane&3 (2 feats each)
__global__ __launch_bounds__(256) void k_pull2(const int* __restrict__ rowptr, const int* __restrict__ rowend,
                                               const int* __restrict__ esrc, const unsigned short* __restrict__ g,
                                               const float* __restrict__ dinv, const float* __restrict__ b2,
                                               float* __restrict__ out, int n) {
    const int tid = threadIdx.x;
    const int slice = blockIdx.x & 7;
    const int wid = tid >> 6;
    const int lane = tid & 63;
    const int eslot = lane >> 2;
    const int fl = lane & 3;
    const int fbase = slice * 8 + fl * 2;
    const int wv = (blockIdx.x >> 3) * 4 + wid;
    const int nwv = (gridDim.x >> 3) * 4;
    const float2 bias = *(const float2*)&b2[fbase];
    for (int node = wv; node < n; node += nwv) {
        const int b = rowptr[node], e = rowend[node];
        float2 a0 = {0.f, 0.f}, a1 = {0.f, 0.f};
        {   // self loop (eslot 0 only)
            float2 s2 = bf2x2(*(const unsigned int*)&g[(size_t)node * 64 + fbase]);
            if (eslot == 0) { a0.x += s2.x; a0.y += s2.y; }
        }
        int j = b;
        for (; j + 32 <= e; j += 32) {
            int s0 = esrc[j + eslot];
            int s1 = esrc[j + 16 + eslot];
            unsigned int v0 = *(const unsigned int*)&g[(size_t)s0 * 64 + fbase];
            unsigned int v1 = *(const unsigned int*)&g[(size_t)s1 * 64 + fbase];
            float2 f0 = bf2x2(v0), f1 = bf2x2(v1);
            a0.x += f0.x; a0.y += f0.y;
            a1.x += f1.x; a1.y += f1.y;
        }
        if (j < e) {  // masked tail (up to 31 edges)
            int i0 = j + eslot;
            bool vv0 = i0 < e;
            int s0 = vv0 ? esrc[i0] : node;
            float2 f0 = bf2x2(*(const unsigned int*)&g[(size_t)s0 * 64 + fbase]);
            if (vv0) { a0.x += f0.x; a0.y += f0.y; }
            int i1 = j + 16 + eslot;
            bool vv1 = i1 < e;
            int s1 = vv1 ? esrc[i1] : node;
            float2 f1 = bf2x2(*(const unsigned int*)&g[(size_t)s1 * 64 + fbase]);
            if (vv1) { a1.x += f1.x; a1.y += f1.y; }
        }
        float2 acc = {a0.x + a1.x, a0.y + a1.y};
        acc.x += __shfl_xor(acc.x, 4);  acc.y += __shfl_xor(acc.y, 4);
        acc.x += __shfl_xor(acc.x, 8);  acc.y += __shfl_xor(acc.y, 8);
        acc.x += __shfl_xor(acc.x, 16); acc.y += __shfl_xor(acc.y, 16);
        acc.x += __shfl_xor(acc.x, 32); acc.y += __shfl_xor(acc.y, 32);
        if (eslot == 0) {
            const float di = dinv[node];
            float2 o = {fmaf(acc.x, di, bias.x), fmaf(acc.y, di, bias.y)};
            *(float2*)&out[(size_t)node * 64 + fbase] = o;
        }
    }
}

extern "C" void kernel_launch(void* const* d_in, const int* in_sizes, int n_in,
                              void* d_out, int out_size, void* d_ws, size_t ws_size,
                              hipStream_t stream) {
    const float* x     = (const float*)d_in[0];
    const int*   ei    = (const int*)d_in[1];
    const float* W1    = (const float*)d_in[2];
    const float* b1    = (const float*)d_in[3];
    const float* gamma = (const float*)d_in[4];
    const float* beta  = (const float*)d_in[5];
    const float* W2    = (const float*)d_in[6];
    const float* b2    = (const float*)d_in[7];
    float* out = (float*)d_out;

    const int n = in_sizes[0] / 128;
    const int E = in_sizes[1] / 2;
    const int* src = ei;
    const int* dst = ei + E;
    const int NB = (n + 127) >> BSH;
    const int Np = (n + 255) & ~255;
    const int Ep = (E + 3) & ~3;

    char* ws = (char*)d_ws;
    int*   gcount = (int*)ws;                 // 1024
    int*   gstart = gcount + 1024;            // 1088 (NB+1)
    int*   cursor = gstart + 1088;            // 1024
    float* stats  = (float*)(cursor + 1024);  // 512
    float* dinv   = stats + 512;              // Np
    int*   rowptr = (int*)(dinv + Np);        // Np
    int*   rowend = rowptr + Np;              // Np
    int2*  pairs  = (int2*)(rowend + Np);     // Ep
    int*   esrc   = (int*)(pairs + Ep);       // Ep
    unsigned short* g1 = (unsigned short*)(esrc + Ep);   // n*128 bf16
    unsigned short* h1 = g1 + (size_t)n * 128;           // n*128 bf16
    unsigned short* g2 = g1;                             // reuse (g1 dead after pull1)

    const int gb = (n + 63) / 64;
    const int gh = (E + 8191) / 8192;
    const int gs = (E + 4095) / 4096;

    hipLaunchKernelGGL(k_zero, dim3(1), dim3(1024), 0, stream, gcount);
    hipLaunchKernelGGL(k_hist, dim3(gh), dim3(256), 0, stream, dst, gcount, E, NB);
    hipLaunchKernelGGL(k_scanb, dim3(1), dim3(1024), 0, stream, gcount, gstart, cursor, stats, NB);
    hipLaunchKernelGGL(k_scatter, dim3(gs), dim3(256), 0, stream, src, dst, cursor, pairs, E, NB);
    hipLaunchKernelGGL(k_build, dim3(NB), dim3(256), 0, stream, pairs, gstart, rowptr, rowend, dinv, esrc, n);

    hipLaunchKernelGGL(k_gemm1, dim3(gb), dim3(256), 0, stream, x, W1, dinv, g1, n);
    hipLaunchKernelGGL(k_pull1, dim3(2048), dim3(256), 0, stream, rowptr, rowend, esrc, g1, dinv, b1, h1, stats, n);
    hipLaunchKernelGGL(k_bnfinal, dim3(1), dim3(128), 0, stream, stats, gamma, beta, n);

    hipLaunchKernelGGL(k_gemm2, dim3(gb), dim3(256), 0, stream, h1, W2, dinv, stats, g2, n);
    hipLaunchKernelGGL(k_pull2, dim3(2048), dim3(256), 0, stream, rowptr, rowend, esrc, g2, dinv, b2, out, n);
}

// Round 10
// 384.509 us; speedup vs baseline: 1.3536x; 1.3536x over previous
//
#include <hip/hip_runtime.h>

constexpr float BN_EPS = 1e-5f;
#define BSH 7          // bucket shift: 128 nodes per bucket
#define NBMAX 1024     // supports n <= 131072

typedef __attribute__((ext_vector_type(8))) short bf16x8;
typedef __attribute__((ext_vector_type(4))) float f32x4;

// bf16 helpers (bit ops; RNE on pack)
__device__ inline float2 bf2x2(unsigned int v) {
    union { unsigned int i; float f; } a, b;
    a.i = v << 16;
    b.i = v & 0xFFFF0000u;
    return make_float2(a.f, b.f);
}
__device__ inline float bf2f(unsigned short u) {
    union { unsigned int i; float f; } a;
    a.i = ((unsigned int)u) << 16;
    return a.f;
}
__device__ inline unsigned short f2bf(float f) {
    union { float f; unsigned int i; } c;
    c.f = f;
    unsigned int i = c.i;
    return (unsigned short)((i + 0x7FFFu + ((i >> 16) & 1u)) >> 16);
}

// swizzled ushort index into a [rows][128] bf16 LDS tile: 16B slot XOR'd by row&7
__device__ inline int wsw(int row, int k) {
    return row * 128 + ((((k >> 3) ^ (row & 7)) << 3) | (k & 7));
}

// ---------------- zero bucket counters ----------------
__global__ void k_zero(int* __restrict__ gcount) {
    gcount[threadIdx.x] = 0;  // 1024 threads
}

// ---------------- phase A1: bucket histogram (LDS-privatized) ----------------
__global__ __launch_bounds__(256) void k_hist(const int* __restrict__ dst, int* __restrict__ gcount,
                                              int E, int NB) {
    __shared__ int lh[NBMAX];
    const int tid = threadIdx.x;
    for (int i = tid; i < NBMAX; i += 256) lh[i] = 0;
    __syncthreads();
    const int base = blockIdx.x * 8192;
#pragma unroll
    for (int i = 0; i < 32; ++i) {
        int e = base + i * 256 + tid;
        if (e < E) atomicAdd(&lh[__builtin_nontemporal_load(&dst[e]) >> BSH], 1);
    }
    __syncthreads();
    for (int b = tid; b < NB; b += 256) {
        int c = lh[b];
        if (c) atomicAdd(&gcount[b], c);
    }
}

// ---------------- phase A2: scan bucket counts; init cursors; zero BN stats ----------------
__global__ __launch_bounds__(1024) void k_scanb(const int* __restrict__ gcount, int* __restrict__ gstart,
                                                int* __restrict__ cursor, float* __restrict__ stats, int NB) {
    __shared__ int tmp[1024];
    const int t = threadIdx.x;
    int v = (t < NB) ? gcount[t] : 0;
    tmp[t] = v;
    __syncthreads();
    for (int off = 1; off < 1024; off <<= 1) {
        int u = (t >= off) ? tmp[t - off] : 0;
        __syncthreads();
        tmp[t] += u;
        __syncthreads();
    }
    if (t < NB) { int ex = tmp[t] - v; gstart[t] = ex; cursor[t] = ex; }
    if (t == NB - 1) gstart[NB] = tmp[t];
    if (t < 512) stats[t] = 0.f;
}

// ---------------- phase A3: scatter edges into bucket-grouped packed ints ----------------
// packed: src (bits 0-19) | dst-local (bits 20-26)
__global__ __launch_bounds__(256) void k_scatter(const int* __restrict__ src, const int* __restrict__ dst,
                                                 int* __restrict__ cursor, int* __restrict__ pairs,
                                                 int E, int NB) {
    __shared__ int lh[NBMAX], lbase[NBMAX], gbase[NBMAX], lcur[NBMAX];
    __shared__ int buf[4096];
    __shared__ unsigned short bo[4096];
    const int tid = threadIdx.x;
    for (int i = tid; i < NBMAX; i += 256) lh[i] = 0;
    __syncthreads();
    const int base = blockIdx.x * 4096;
    const int cnt = min(4096, E - base);
#pragma unroll
    for (int i = 0; i < 16; ++i) {
        int e = base + i * 256 + tid;
        if (e < E) atomicAdd(&lh[__builtin_nontemporal_load(&dst[e]) >> BSH], 1);
    }
    __syncthreads();
    int s0 = lh[tid * 4], s1 = lh[tid * 4 + 1], s2 = lh[tid * 4 + 2], s3 = lh[tid * 4 + 3];
    int ts = s0 + s1 + s2 + s3;
    lcur[tid] = ts;
    __syncthreads();
    for (int off = 1; off < 256; off <<= 1) {
        int u = (tid >= off) ? lcur[tid - off] : 0;
        __syncthreads();
        lcur[tid] += u;
        __syncthreads();
    }
    int ex = lcur[tid] - ts;
    lbase[tid * 4] = ex;
    lbase[tid * 4 + 1] = ex + s0;
    lbase[tid * 4 + 2] = ex + s0 + s1;
    lbase[tid * 4 + 3] = ex + s0 + s1 + s2;
    __syncthreads();
    for (int b = tid; b < NB; b += 256) {
        int c = lh[b];
        gbase[b] = c ? atomicAdd(&cursor[b], c) : 0;
    }
    for (int i = tid; i < NBMAX; i += 256) lcur[i] = 0;
    __syncthreads();
#pragma unroll
    for (int i = 0; i < 16; ++i) {
        int e = base + i * 256 + tid;
        if (e < E) {
            int d = dst[e];
            int b = d >> BSH;
            int p = lbase[b] + atomicAdd(&lcur[b], 1);
            buf[p] = src[e] | ((d & ((1 << BSH) - 1)) << 20);
            bo[p] = (unsigned short)b;
        }
    }
    __syncthreads();
#pragma unroll
    for (int i = 0; i < 16; ++i) {
        int p = i * 256 + tid;
        if (p < cnt) {
            int b = bo[p];
            __builtin_nontemporal_store(buf[p], &pairs[gbase[b] + (p - lbase[b])]);
        }
    }
}

// ---------------- phase B: per-bucket fine sort -> rowptr/rowend/dinv/esrc ----------------
__global__ __launch_bounds__(256) void k_build(const int* __restrict__ pairs, const int* __restrict__ gstart,
                                               int* __restrict__ rowptr, int* __restrict__ rowend,
                                               float* __restrict__ dinv, int* __restrict__ esrc, int n) {
    __shared__ int lh[128], lsc[128], lcur[128];
    const int tid = threadIdx.x;
    const int b = blockIdx.x;
    const int e0 = gstart[b], e1 = gstart[b + 1];
    const int node0 = b << BSH;
    if (tid < 128) lh[tid] = 0;
    __syncthreads();
    for (int e = e0 + tid; e < e1; e += 256) atomicAdd(&lh[pairs[e] >> 20], 1);
    __syncthreads();
    int v = (tid < 128) ? lh[tid] : 0;
    if (tid < 128) lsc[tid] = v;
    __syncthreads();
    for (int off = 1; off < 128; off <<= 1) {
        int u = (tid >= off && tid < 128) ? lsc[tid - off] : 0;
        __syncthreads();
        if (tid < 128) lsc[tid] += u;
        __syncthreads();
    }
    if (tid < 128) {
        int ex = lsc[tid] - v;
        lcur[tid] = ex;
        int node = node0 + tid;
        if (node < n) {
            int rp = e0 + ex;
            rowptr[node] = rp;
            rowend[node] = rp + v;
            dinv[node] = rsqrtf((float)(v + 1));  // +1 self loop
        }
    }
    __syncthreads();
    for (int e = e0 + tid; e < e1; e += 256) {
        int pv = pairs[e];
        int pos = atomicAdd(&lcur[pv >> 20], 1);
        __builtin_nontemporal_store(pv & 0xFFFFF, &esrc[e0 + pos]);
    }
}

// ---------------- GEMM1 (MFMA): g1 = bf16( dinv ⊙ (x @ W1^T) ) ----------------
__global__ __launch_bounds__(256) void k_gemm1(const float* __restrict__ x,
                                               const float* __restrict__ W1,
                                               const float* __restrict__ dinv,
                                               unsigned short* __restrict__ g1, int n) {
    __shared__ unsigned short Ws[128 * 128];
    const int tid = threadIdx.x;
#pragma unroll
    for (int i = 0; i < 16; ++i) {
        int idx4 = i * 256 + tid;
        int j = idx4 >> 5;
        int k = (idx4 & 31) * 4;
        float4 v = *(const float4*)&W1[(size_t)j * 128 + k];
        ushort4 u;
        u.x = f2bf(v.x); u.y = f2bf(v.y); u.z = f2bf(v.z); u.w = f2bf(v.w);
        *(ushort2*)&Ws[wsw(j, k)] = make_ushort2(u.x, u.y);
        *(ushort2*)&Ws[wsw(j, k + 2)] = make_ushort2(u.z, u.w);
    }
    __syncthreads();
    const int wave = tid >> 6, l = tid & 63;
    const int am = l & 15;
    const int kg = l >> 4;
    const int row0 = blockIdx.x * 64 + wave * 16;
    const int grow = row0 + am;
    const float* xrow = &x[(size_t)(grow < n ? grow : 0) * 128];
    f32x4 acc[8] = {};
#pragma unroll
    for (int k0 = 0; k0 < 128; k0 += 32) {
        const int kk = k0 + kg * 8;
        float4 a0 = *(const float4*)&xrow[kk];
        float4 a1 = *(const float4*)&xrow[kk + 4];
        union { unsigned short u[8]; bf16x8 v; } af;
        af.u[0] = f2bf(a0.x); af.u[1] = f2bf(a0.y); af.u[2] = f2bf(a0.z); af.u[3] = f2bf(a0.w);
        af.u[4] = f2bf(a1.x); af.u[5] = f2bf(a1.y); af.u[6] = f2bf(a1.z); af.u[7] = f2bf(a1.w);
#pragma unroll
        for (int ct = 0; ct < 8; ++ct) {
            union { uint4 q; bf16x8 v; } bf;
            bf.q = *(const uint4*)&Ws[wsw(ct * 16 + am, kk)];
            acc[ct] = __builtin_amdgcn_mfma_f32_16x16x32_bf16(af.v, bf.v, acc[ct], 0, 0, 0);
        }
    }
#pragma unroll
    for (int r = 0; r < 4; ++r) {
        int orow = row0 + kg * 4 + r;
        if (orow < n) {
            float di = dinv[orow];
#pragma unroll
            for (int ct = 0; ct < 8; ++ct)
                g1[(size_t)orow * 128 + ct * 16 + am] = f2bf(acc[ct][r] * di);
        }
    }
}

// ---------------- pull1: h1(bf16) = dinv*(g1[d] + sum g1[src]) + b1 ; BN stats ----------------
__global__ __launch_bounds__(256) void k_pull1(const int* __restrict__ rowptr, const int* __restrict__ rowend,
                                               const int* __restrict__ esrc, const unsigned short* __restrict__ g,
                                               const float* __restrict__ dinv, const float* __restrict__ b1,
                                               unsigned short* __restrict__ h1, float* __restrict__ stats, int n) {
    __shared__ float2 sSum[4][64];
    __shared__ float2 sSq[4][64];
    const int wid = threadIdx.x >> 6, lane = threadIdx.x & 63;
    const int gw = blockIdx.x * 4 + wid;
    const int nw = gridDim.x * 4;
    const float2 bias = *(const float2*)&b1[lane * 2];
    float2 psum = {0.f, 0.f}, psq = {0.f, 0.f};
    for (int node = gw; node < n; node += nw) {
        const int b = rowptr[node], e = rowend[node];
        float2 a0 = bf2x2(*(const unsigned int*)&g[(size_t)node * 128 + lane * 2]);  // self loop
        float2 a1 = {0.f, 0.f}, a2 = {0.f, 0.f}, a3 = {0.f, 0.f};
        float2 a4 = {0.f, 0.f}, a5 = {0.f, 0.f}, a6 = {0.f, 0.f}, a7 = {0.f, 0.f};
        int j = b;
        for (; j + 8 <= e; j += 8) {
            int s0 = __builtin_nontemporal_load(&esrc[j + 0]);
            int s1 = __builtin_nontemporal_load(&esrc[j + 1]);
            int s2 = __builtin_nontemporal_load(&esrc[j + 2]);
            int s3 = __builtin_nontemporal_load(&esrc[j + 3]);
            int s4 = __builtin_nontemporal_load(&esrc[j + 4]);
            int s5 = __builtin_nontemporal_load(&esrc[j + 5]);
            int s6 = __builtin_nontemporal_load(&esrc[j + 6]);
            int s7 = __builtin_nontemporal_load(&esrc[j + 7]);
            unsigned int v0 = *(const unsigned int*)&g[(size_t)s0 * 128 + lane * 2];
            unsigned int v1 = *(const unsigned int*)&g[(size_t)s1 * 128 + lane * 2];
            unsigned int v2 = *(const unsigned int*)&g[(size_t)s2 * 128 + lane * 2];
            unsigned int v3 = *(const unsigned int*)&g[(size_t)s3 * 128 + lane * 2];
            unsigned int v4 = *(const unsigned int*)&g[(size_t)s4 * 128 + lane * 2];
            unsigned int v5 = *(const unsigned int*)&g[(size_t)s5 * 128 + lane * 2];
            unsigned int v6 = *(const unsigned int*)&g[(size_t)s6 * 128 + lane * 2];
            unsigned int v7 = *(const unsigned int*)&g[(size_t)s7 * 128 + lane * 2];
            float2 f0 = bf2x2(v0), f1 = bf2x2(v1), f2 = bf2x2(v2), f3 = bf2x2(v3);
            float2 f4 = bf2x2(v4), f5 = bf2x2(v5), f6 = bf2x2(v6), f7 = bf2x2(v7);
            a0.x += f0.x; a0.y += f0.y;
            a1.x += f1.x; a1.y += f1.y;
            a2.x += f2.x; a2.y += f2.y;
            a3.x += f3.x; a3.y += f3.y;
            a4.x += f4.x; a4.y += f4.y;
            a5.x += f5.x; a5.y += f5.y;
            a6.x += f6.x; a6.y += f6.y;
            a7.x += f7.x; a7.y += f7.y;
        }
        for (; j < e; ++j) {
            int s = __builtin_nontemporal_load(&esrc[j]);
            float2 v = bf2x2(*(const unsigned int*)&g[(size_t)s * 128 + lane * 2]);
            a0.x += v.x; a0.y += v.y;
        }
        float2 acc = {((a0.x + a1.x) + (a2.x + a3.x)) + ((a4.x + a5.x) + (a6.x + a7.x)),
                      ((a0.y + a1.y) + (a2.y + a3.y)) + ((a4.y + a5.y) + (a6.y + a7.y))};
        const float di = dinv[node];
        float2 hv = {fmaf(acc.x, di, bias.x), fmaf(acc.y, di, bias.y)};
        unsigned int pk = ((unsigned int)f2bf(hv.y) << 16) | (unsigned int)f2bf(hv.x);
        __builtin_nontemporal_store(pk, (unsigned int*)&h1[(size_t)node * 128 + lane * 2]);
        psum.x += hv.x; psum.y += hv.y;
        psq.x = fmaf(hv.x, hv.x, psq.x);
        psq.y = fmaf(hv.y, hv.y, psq.y);
    }
    sSum[wid][lane] = psum;
    sSq[wid][lane] = psq;
    __syncthreads();
    if (threadIdx.x < 64) {
        float2 a = sSum[0][lane], b = sSum[1][lane], c = sSum[2][lane], d = sSum[3][lane];
        atomicAdd(&stats[lane * 2 + 0], a.x + b.x + c.x + d.x);
        atomicAdd(&stats[lane * 2 + 1], a.y + b.y + c.y + d.y);
        a = sSq[0][lane]; b = sSq[1][lane]; c = sSq[2][lane]; d = sSq[3][lane];
        atomicAdd(&stats[128 + lane * 2 + 0], a.x + b.x + c.x + d.x);
        atomicAdd(&stats[128 + lane * 2 + 1], a.y + b.y + c.y + d.y);
    }
}

// ---------------- GEMM2 (MFMA, fused BN-final): g2 = bf16( dinv ⊙ (relu(BN(h1)) @ W2^T) ) ----------------
__global__ __launch_bounds__(256) void k_gemm2(const unsigned short* __restrict__ h1,
                                               const float* __restrict__ W2,
                                               const float* __restrict__ dinv,
                                               const float* __restrict__ stats,
                                               const float* __restrict__ gamma,
                                               const float* __restrict__ beta,
                                               unsigned short* __restrict__ g2, int n) {
    __shared__ unsigned short Ws[64 * 128];
    __shared__ float sSc[128], sSh[128];
    const int tid = threadIdx.x;
    if (tid < 128) {  // fused BN scale/shift from sums
        float inv_n = 1.f / (float)n;
        float mean = stats[tid] * inv_n;
        float var = stats[128 + tid] * inv_n - mean * mean;
        float sc = gamma[tid] * rsqrtf(var + BN_EPS);
        sSc[tid] = sc;
        sSh[tid] = fmaf(-mean, sc, beta[tid]);
    }
#pragma unroll
    for (int i = 0; i < 8; ++i) {
        int idx4 = i * 256 + tid;
        int j = idx4 >> 5;
        int k = (idx4 & 31) * 4;
        float4 v = *(const float4*)&W2[(size_t)j * 128 + k];
        ushort4 u;
        u.x = f2bf(v.x); u.y = f2bf(v.y); u.z = f2bf(v.z); u.w = f2bf(v.w);
        *(ushort2*)&Ws[wsw(j, k)] = make_ushort2(u.x, u.y);
        *(ushort2*)&Ws[wsw(j, k + 2)] = make_ushort2(u.z, u.w);
    }
    __syncthreads();
    const int wave = tid >> 6, l = tid & 63;
    const int am = l & 15;
    const int kg = l >> 4;
    const int row0 = blockIdx.x * 64 + wave * 16;
    const int grow = row0 + am;
    const unsigned short* hrow = &h1[(size_t)(grow < n ? grow : 0) * 128];
    f32x4 acc[4] = {};
#pragma unroll
    for (int k0 = 0; k0 < 128; k0 += 32) {
        const int kk = k0 + kg * 8;
        uint4 hq = *(const uint4*)&hrow[kk];
        float2 p0 = bf2x2(hq.x), p1 = bf2x2(hq.y), p2 = bf2x2(hq.z), p3 = bf2x2(hq.w);
        float hf[8] = {p0.x, p0.y, p1.x, p1.y, p2.x, p2.y, p3.x, p3.y};
        float4 sc0 = *(const float4*)&sSc[kk];
        float4 sc1 = *(const float4*)&sSc[kk + 4];
        float4 sh0 = *(const float4*)&sSh[kk];
        float4 sh1 = *(const float4*)&sSh[kk + 4];
        float scv[8] = {sc0.x, sc0.y, sc0.z, sc0.w, sc1.x, sc1.y, sc1.z, sc1.w};
        float shv[8] = {sh0.x, sh0.y, sh0.z, sh0.w, sh1.x, sh1.y, sh1.z, sh1.w};
        union { unsigned short u[8]; bf16x8 v; } af;
#pragma unroll
        for (int jj = 0; jj < 8; ++jj)
            af.u[jj] = f2bf(fmaxf(fmaf(hf[jj], scv[jj], shv[jj]), 0.f));
#pragma unroll
        for (int ct = 0; ct < 4; ++ct) {
            union { uint4 q; bf16x8 v; } bf;
            bf.q = *(const uint4*)&Ws[wsw(ct * 16 + am, kk)];
            acc[ct] = __builtin_amdgcn_mfma_f32_16x16x32_bf16(af.v, bf.v, acc[ct], 0, 0, 0);
        }
    }
#pragma unroll
    for (int r = 0; r < 4; ++r) {
        int orow = row0 + kg * 4 + r;
        if (orow < n) {
            float di = dinv[orow];
#pragma unroll
            for (int ct = 0; ct < 4; ++ct)
                g2[(size_t)orow * 64 + ct * 16 + am] = f2bf(acc[ct][r] * di);
        }
    }
}

// ---------------- pull2: out[d] = dinv[d]*(g2[d] + sum g2[src]) + b2 ----------------
__global__ __launch_bounds__(256) void k_pull2(const int* __restrict__ rowptr, const int* __restrict__ rowend,
                                               const int* __restrict__ esrc, const unsigned short* __restrict__ g,
                                               const float* __restrict__ dinv, const float* __restrict__ b2,
                                               float* __restrict__ out, int n) {
    const int wid = threadIdx.x >> 6, lane = threadIdx.x & 63;
    const int gw = blockIdx.x * 4 + wid;
    const int nw = gridDim.x * 4;
    const float bias = b2[lane];
    for (int node = gw; node < n; node += nw) {
        const int b = rowptr[node], e = rowend[node];
        float a0 = bf2f(g[(size_t)node * 64 + lane]);  // self loop
        float a1 = 0.f, a2 = 0.f, a3 = 0.f, a4 = 0.f, a5 = 0.f, a6 = 0.f, a7 = 0.f;
        int j = b;
        for (; j + 8 <= e; j += 8) {
            int s0 = __builtin_nontemporal_load(&esrc[j + 0]);
            int s1 = __builtin_nontemporal_load(&esrc[j + 1]);
            int s2 = __builtin_nontemporal_load(&esrc[j + 2]);
            int s3 = __builtin_nontemporal_load(&esrc[j + 3]);
            int s4 = __builtin_nontemporal_load(&esrc[j + 4]);
            int s5 = __builtin_nontemporal_load(&esrc[j + 5]);
            int s6 = __builtin_nontemporal_load(&esrc[j + 6]);
            int s7 = __builtin_nontemporal_load(&esrc[j + 7]);
            unsigned short v0 = g[(size_t)s0 * 64 + lane];
            unsigned short v1 = g[(size_t)s1 * 64 + lane];
            unsigned short v2 = g[(size_t)s2 * 64 + lane];
            unsigned short v3 = g[(size_t)s3 * 64 + lane];
            unsigned short v4 = g[(size_t)s4 * 64 + lane];
            unsigned short v5 = g[(size_t)s5 * 64 + lane];
            unsigned short v6 = g[(size_t)s6 * 64 + lane];
            unsigned short v7 = g[(size_t)s7 * 64 + lane];
            a0 += bf2f(v0); a1 += bf2f(v1); a2 += bf2f(v2); a3 += bf2f(v3);
            a4 += bf2f(v4); a5 += bf2f(v5); a6 += bf2f(v6); a7 += bf2f(v7);
        }
        for (; j < e; ++j) a0 += bf2f(g[(size_t)__builtin_nontemporal_load(&esrc[j]) * 64 + lane]);
        float acc = ((a0 + a1) + (a2 + a3)) + ((a4 + a5) + (a6 + a7));
        __builtin_nontemporal_store(fmaf(acc, dinv[node], bias), &out[(size_t)node * 64 + lane]);
    }
}

extern "C" void kernel_launch(void* const* d_in, const int* in_sizes, int n_in,
                              void* d_out, int out_size, void* d_ws, size_t ws_size,
                              hipStream_t stream) {
    const float* x     = (const float*)d_in[0];
    const int*   ei    = (const int*)d_in[1];
    const float* W1    = (const float*)d_in[2];
    const float* b1    = (const float*)d_in[3];
    const float* gamma = (const float*)d_in[4];
    const float* beta  = (const float*)d_in[5];
    const float* W2    = (const float*)d_in[6];
    const float* b2    = (const float*)d_in[7];
    float* out = (float*)d_out;

    const int n = in_sizes[0] / 128;
    const int E = in_sizes[1] / 2;
    const int* src = ei;
    const int* dst = ei + E;
    const int NB = (n + 127) >> BSH;
    const int Np = (n + 255) & ~255;
    const int Ep = (E + 3) & ~3;

    char* ws = (char*)d_ws;
    int*   gcount = (int*)ws;                 // 1024
    int*   gstart = gcount + 1024;            // 1088 (NB+1)
    int*   cursor = gstart + 1088;            // 1024
    float* stats  = (float*)(cursor + 1024);  // 512: [0,128)sum [128,256)sumsq
    float* dinv   = stats + 512;              // Np
    int*   rowptr = (int*)(dinv + Np);        // Np
    int*   rowend = rowptr + Np;              // Np
    int*   pairs  = rowend + Np;              // Ep (packed src|dlocal<<20)
    int*   esrc   = pairs + Ep;               // Ep
    unsigned short* g1 = (unsigned short*)(esrc + Ep);   // n*128 bf16
    unsigned short* h1 = g1 + (size_t)n * 128;           // n*128 bf16
    unsigned short* g2 = g1;                             // reuse (g1 dead after pull1)

    const int gb = (n + 63) / 64;
    const int gh = (E + 8191) / 8192;
    const int gs = (E + 4095) / 4096;

    hipLaunchKernelGGL(k_zero, dim3(1), dim3(1024), 0, stream, gcount);
    hipLaunchKernelGGL(k_hist, dim3(gh), dim3(256), 0, stream, dst, gcount, E, NB);
    hipLaunchKernelGGL(k_scanb, dim3(1), dim3(1024), 0, stream, gcount, gstart, cursor, stats, NB);
    hipLaunchKernelGGL(k_scatter, dim3(gs), dim3(256), 0, stream, src, dst, cursor, pairs, E, NB);
    hipLaunchKernelGGL(k_build, dim3(NB), dim3(256), 0, stream, pairs, gstart, rowptr, rowend, dinv, esrc, n);

    hipLaunchKernelGGL(k_gemm1, dim3(gb), dim3(256), 0, stream, x, W1, dinv, g1, n);
    hipLaunchKernelGGL(k_pull1, dim3(2048), dim3(256), 0, stream, rowptr, rowend, esrc, g1, dinv, b1, h1, stats, n);

    hipLaunchKernelGGL(k_gemm2, dim3(gb), dim3(256), 0, stream, h1, W2, dinv, stats, gamma, beta, g2, n);
    hipLaunchKernelGGL(k_pull2, dim3(2048), dim3(256), 0, stream, rowptr, rowend, esrc, g2, dinv, b2, out, n);
}

// Round 11
// 314.074 us; speedup vs baseline: 1.6572x; 1.2243x over previous
//
#include <hip/hip_runtime.h>

constexpr float BN_EPS = 1e-5f;
#define BSH 7          // bucket shift: 128 nodes per bucket
#define NBMAX 1024     // supports n <= 131072

typedef __attribute__((ext_vector_type(8))) short bf16x8;
typedef __attribute__((ext_vector_type(4))) float f32x4;

// bf16 helpers (bit ops; RNE on pack)
__device__ inline float2 bf2x2(unsigned int v) {
    union { unsigned int i; float f; } a, b;
    a.i = v << 16;
    b.i = v & 0xFFFF0000u;
    return make_float2(a.f, b.f);
}
__device__ inline float bf2f(unsigned short u) {
    union { unsigned int i; float f; } a;
    a.i = ((unsigned int)u) << 16;
    return a.f;
}
__device__ inline unsigned short f2bf(float f) {
    union { float f; unsigned int i; } c;
    c.f = f;
    unsigned int i = c.i;
    return (unsigned short)((i + 0x7FFFu + ((i >> 16) & 1u)) >> 16);
}

// swizzled ushort index into a [rows][128] bf16 LDS tile: 16B slot XOR'd by row&7
__device__ inline int wsw(int row, int k) {
    return row * 128 + ((((k >> 3) ^ (row & 7)) << 3) | (k & 7));
}

// ---------------- zero bucket counters ----------------
__global__ void k_zero(int* __restrict__ gcount) {
    gcount[threadIdx.x] = 0;  // 1024 threads
}

// ---------------- phase A1: bucket histogram (LDS-privatized) ----------------
__global__ __launch_bounds__(256) void k_hist(const int* __restrict__ dst, int* __restrict__ gcount,
                                              int E, int NB) {
    __shared__ int lh[NBMAX];
    const int tid = threadIdx.x;
    for (int i = tid; i < NBMAX; i += 256) lh[i] = 0;
    __syncthreads();
    const int base = blockIdx.x * 8192;
#pragma unroll
    for (int i = 0; i < 32; ++i) {
        int e = base + i * 256 + tid;
        if (e < E) atomicAdd(&lh[dst[e] >> BSH], 1);
    }
    __syncthreads();
    for (int b = tid; b < NB; b += 256) {
        int c = lh[b];
        if (c) atomicAdd(&gcount[b], c);
    }
}

// ---------------- phase A2: scan bucket counts; init cursors; zero BN stats ----------------
__global__ __launch_bounds__(1024) void k_scanb(const int* __restrict__ gcount, int* __restrict__ gstart,
                                                int* __restrict__ cursor, float* __restrict__ stats, int NB) {
    __shared__ int tmp[1024];
    const int t = threadIdx.x;
    int v = (t < NB) ? gcount[t] : 0;
    tmp[t] = v;
    __syncthreads();
    for (int off = 1; off < 1024; off <<= 1) {
        int u = (t >= off) ? tmp[t - off] : 0;
        __syncthreads();
        tmp[t] += u;
        __syncthreads();
    }
    if (t < NB) { int ex = tmp[t] - v; gstart[t] = ex; cursor[t] = ex; }
    if (t == NB - 1) gstart[NB] = tmp[t];
    if (t < 512) stats[t] = 0.f;
}

// ---------------- phase A3: scatter edges into bucket-grouped packed ints ----------------
// packed: src (bits 0-19) | dst-local (bits 20-26)
__global__ __launch_bounds__(256) void k_scatter(const int* __restrict__ src, const int* __restrict__ dst,
                                                 int* __restrict__ cursor, int* __restrict__ pairs,
                                                 int E, int NB) {
    __shared__ int lh[NBMAX], lbase[NBMAX], gbase[NBMAX], lcur[NBMAX];
    __shared__ int buf[4096];
    __shared__ unsigned short bo[4096];
    const int tid = threadIdx.x;
    for (int i = tid; i < NBMAX; i += 256) lh[i] = 0;
    __syncthreads();
    const int base = blockIdx.x * 4096;
    const int cnt = min(4096, E - base);
#pragma unroll
    for (int i = 0; i < 16; ++i) {
        int e = base + i * 256 + tid;
        if (e < E) atomicAdd(&lh[dst[e] >> BSH], 1);
    }
    __syncthreads();
    int s0 = lh[tid * 4], s1 = lh[tid * 4 + 1], s2 = lh[tid * 4 + 2], s3 = lh[tid * 4 + 3];
    int ts = s0 + s1 + s2 + s3;
    lcur[tid] = ts;
    __syncthreads();
    for (int off = 1; off < 256; off <<= 1) {
        int u = (tid >= off) ? lcur[tid - off] : 0;
        __syncthreads();
        lcur[tid] += u;
        __syncthreads();
    }
    int ex = lcur[tid] - ts;
    lbase[tid * 4] = ex;
    lbase[tid * 4 + 1] = ex + s0;
    lbase[tid * 4 + 2] = ex + s0 + s1;
    lbase[tid * 4 + 3] = ex + s0 + s1 + s2;
    __syncthreads();
    for (int b = tid; b < NB; b += 256) {
        int c = lh[b];
        gbase[b] = c ? atomicAdd(&cursor[b], c) : 0;
    }
    for (int i = tid; i < NBMAX; i += 256) lcur[i] = 0;
    __syncthreads();
#pragma unroll
    for (int i = 0; i < 16; ++i) {
        int e = base + i * 256 + tid;
        if (e < E) {
            int d = dst[e];
            int b = d >> BSH;
            int p = lbase[b] + atomicAdd(&lcur[b], 1);
            buf[p] = src[e] | ((d & ((1 << BSH) - 1)) << 20);
            bo[p] = (unsigned short)b;
        }
    }
    __syncthreads();
#pragma unroll
    for (int i = 0; i < 16; ++i) {
        int p = i * 256 + tid;
        if (p < cnt) {
            int b = bo[p];
            pairs[gbase[b] + (p - lbase[b])] = buf[p];
        }
    }
}

// ---------------- phase B: per-bucket fine sort -> rowptr/rowend/dinv/esrc ----------------
__global__ __launch_bounds__(256) void k_build(const int* __restrict__ pairs, const int* __restrict__ gstart,
                                               int* __restrict__ rowptr, int* __restrict__ rowend,
                                               float* __restrict__ dinv, int* __restrict__ esrc, int n) {
    __shared__ int lh[128], lsc[128], lcur[128];
    const int tid = threadIdx.x;
    const int b = blockIdx.x;
    const int e0 = gstart[b], e1 = gstart[b + 1];
    const int node0 = b << BSH;
    if (tid < 128) lh[tid] = 0;
    __syncthreads();
    for (int e = e0 + tid; e < e1; e += 256) atomicAdd(&lh[pairs[e] >> 20], 1);
    __syncthreads();
    int v = (tid < 128) ? lh[tid] : 0;
    if (tid < 128) lsc[tid] = v;
    __syncthreads();
    for (int off = 1; off < 128; off <<= 1) {
        int u = (tid >= off && tid < 128) ? lsc[tid - off] : 0;
        __syncthreads();
        if (tid < 128) lsc[tid] += u;
        __syncthreads();
    }
    if (tid < 128) {
        int ex = lsc[tid] - v;
        lcur[tid] = ex;
        int node = node0 + tid;
        if (node < n) {
            int rp = e0 + ex;
            rowptr[node] = rp;
            rowend[node] = rp + v;
            dinv[node] = rsqrtf((float)(v + 1));  // +1 self loop
        }
    }
    __syncthreads();
    for (int e = e0 + tid; e < e1; e += 256) {
        int pv = pairs[e];
        int pos = atomicAdd(&lcur[pv >> 20], 1);
        esrc[e0 + pos] = pv & 0xFFFFF;
    }
}

// ---------------- GEMM1 (MFMA): g1 = bf16( dinv ⊙ (x @ W1^T) ) ----------------
__global__ __launch_bounds__(256) void k_gemm1(const float* __restrict__ x,
                                               const float* __restrict__ W1,
                                               const float* __restrict__ dinv,
                                               unsigned short* __restrict__ g1, int n) {
    __shared__ unsigned short Ws[128 * 128];
    const int tid = threadIdx.x;
#pragma unroll
    for (int i = 0; i < 16; ++i) {
        int idx4 = i * 256 + tid;
        int j = idx4 >> 5;
        int k = (idx4 & 31) * 4;
        float4 v = *(const float4*)&W1[(size_t)j * 128 + k];
        ushort4 u;
        u.x = f2bf(v.x); u.y = f2bf(v.y); u.z = f2bf(v.z); u.w = f2bf(v.w);
        *(ushort2*)&Ws[wsw(j, k)] = make_ushort2(u.x, u.y);
        *(ushort2*)&Ws[wsw(j, k + 2)] = make_ushort2(u.z, u.w);
    }
    __syncthreads();
    const int wave = tid >> 6, l = tid & 63;
    const int am = l & 15;
    const int kg = l >> 4;
    const int row0 = blockIdx.x * 64 + wave * 16;
    const int grow = row0 + am;
    const float* xrow = &x[(size_t)(grow < n ? grow : 0) * 128];
    f32x4 acc[8] = {};
#pragma unroll
    for (int k0 = 0; k0 < 128; k0 += 32) {
        const int kk = k0 + kg * 8;
        float4 a0 = *(const float4*)&xrow[kk];
        float4 a1 = *(const float4*)&xrow[kk + 4];
        union { unsigned short u[8]; bf16x8 v; } af;
        af.u[0] = f2bf(a0.x); af.u[1] = f2bf(a0.y); af.u[2] = f2bf(a0.z); af.u[3] = f2bf(a0.w);
        af.u[4] = f2bf(a1.x); af.u[5] = f2bf(a1.y); af.u[6] = f2bf(a1.z); af.u[7] = f2bf(a1.w);
#pragma unroll
        for (int ct = 0; ct < 8; ++ct) {
            union { uint4 q; bf16x8 v; } bf;
            bf.q = *(const uint4*)&Ws[wsw(ct * 16 + am, kk)];
            acc[ct] = __builtin_amdgcn_mfma_f32_16x16x32_bf16(af.v, bf.v, acc[ct], 0, 0, 0);
        }
    }
#pragma unroll
    for (int r = 0; r < 4; ++r) {
        int orow = row0 + kg * 4 + r;
        if (orow < n) {
            float di = dinv[orow];
#pragma unroll
            for (int ct = 0; ct < 8; ++ct)
                g1[(size_t)orow * 128 + ct * 16 + am] = f2bf(acc[ct][r] * di);
        }
    }
}

// ---------------- pull1: h1(bf16) = dinv*(g1[d] + sum g1[src]) + b1 ; BN stats ----------------
__global__ __launch_bounds__(256) void k_pull1(const int* __restrict__ rowptr, const int* __restrict__ rowend,
                                               const int* __restrict__ esrc, const unsigned short* __restrict__ g,
                                               const float* __restrict__ dinv, const float* __restrict__ b1,
                                               unsigned short* __restrict__ h1, float* __restrict__ stats, int n) {
    __shared__ float2 sSum[4][64];
    __shared__ float2 sSq[4][64];
    const int wid = threadIdx.x >> 6, lane = threadIdx.x & 63;
    const int gw = blockIdx.x * 4 + wid;
    const int nw = gridDim.x * 4;
    const float2 bias = *(const float2*)&b1[lane * 2];
    float2 psum = {0.f, 0.f}, psq = {0.f, 0.f};
    for (int node = gw; node < n; node += nw) {
        const int b = rowptr[node], e = rowend[node];
        float2 a0 = bf2x2(*(const unsigned int*)&g[(size_t)node * 128 + lane * 2]);  // self loop
        float2 a1 = {0.f, 0.f}, a2 = {0.f, 0.f}, a3 = {0.f, 0.f};
        float2 a4 = {0.f, 0.f}, a5 = {0.f, 0.f}, a6 = {0.f, 0.f}, a7 = {0.f, 0.f};
        int j = b;
        for (; j + 8 <= e; j += 8) {
            int s0 = esrc[j + 0], s1 = esrc[j + 1], s2 = esrc[j + 2], s3 = esrc[j + 3];
            int s4 = esrc[j + 4], s5 = esrc[j + 5], s6 = esrc[j + 6], s7 = esrc[j + 7];
            unsigned int v0 = *(const unsigned int*)&g[(size_t)s0 * 128 + lane * 2];
            unsigned int v1 = *(const unsigned int*)&g[(size_t)s1 * 128 + lane * 2];
            unsigned int v2 = *(const unsigned int*)&g[(size_t)s2 * 128 + lane * 2];
            unsigned int v3 = *(const unsigned int*)&g[(size_t)s3 * 128 + lane * 2];
            unsigned int v4 = *(const unsigned int*)&g[(size_t)s4 * 128 + lane * 2];
            unsigned int v5 = *(const unsigned int*)&g[(size_t)s5 * 128 + lane * 2];
            unsigned int v6 = *(const unsigned int*)&g[(size_t)s6 * 128 + lane * 2];
            unsigned int v7 = *(const unsigned int*)&g[(size_t)s7 * 128 + lane * 2];
            float2 f0 = bf2x2(v0), f1 = bf2x2(v1), f2 = bf2x2(v2), f3 = bf2x2(v3);
            float2 f4 = bf2x2(v4), f5 = bf2x2(v5), f6 = bf2x2(v6), f7 = bf2x2(v7);
            a0.x += f0.x; a0.y += f0.y;
            a1.x += f1.x; a1.y += f1.y;
            a2.x += f2.x; a2.y += f2.y;
            a3.x += f3.x; a3.y += f3.y;
            a4.x += f4.x; a4.y += f4.y;
            a5.x += f5.x; a5.y += f5.y;
            a6.x += f6.x; a6.y += f6.y;
            a7.x += f7.x; a7.y += f7.y;
        }
        for (; j < e; ++j) {
            int s = esrc[j];
            float2 v = bf2x2(*(const unsigned int*)&g[(size_t)s * 128 + lane * 2]);
            a0.x += v.x; a0.y += v.y;
        }
        float2 acc = {((a0.x + a1.x) + (a2.x + a3.x)) + ((a4.x + a5.x) + (a6.x + a7.x)),
                      ((a0.y + a1.y) + (a2.y + a3.y)) + ((a4.y + a5.y) + (a6.y + a7.y))};
        const float di = dinv[node];
        float2 hv = {fmaf(acc.x, di, bias.x), fmaf(acc.y, di, bias.y)};
        unsigned int pk = ((unsigned int)f2bf(hv.y) << 16) | (unsigned int)f2bf(hv.x);
        *(unsigned int*)&h1[(size_t)node * 128 + lane * 2] = pk;
        psum.x += hv.x; psum.y += hv.y;
        psq.x = fmaf(hv.x, hv.x, psq.x);
        psq.y = fmaf(hv.y, hv.y, psq.y);
    }
    sSum[wid][lane] = psum;
    sSq[wid][lane] = psq;
    __syncthreads();
    if (threadIdx.x < 64) {
        float2 a = sSum[0][lane], b = sSum[1][lane], c = sSum[2][lane], d = sSum[3][lane];
        atomicAdd(&stats[lane * 2 + 0], a.x + b.x + c.x + d.x);
        atomicAdd(&stats[lane * 2 + 1], a.y + b.y + c.y + d.y);
        a = sSq[0][lane]; b = sSq[1][lane]; c = sSq[2][lane]; d = sSq[3][lane];
        atomicAdd(&stats[128 + lane * 2 + 0], a.x + b.x + c.x + d.x);
        atomicAdd(&stats[128 + lane * 2 + 1], a.y + b.y + c.y + d.y);
    }
}

// ---------------- GEMM2 (MFMA, fused BN-final): g2 = bf16( dinv ⊙ (relu(BN(h1)) @ W2^T) ) ----------------
__global__ __launch_bounds__(256) void k_gemm2(const unsigned short* __restrict__ h1,
                                               const float* __restrict__ W2,
                                               const float* __restrict__ dinv,
                                               const float* __restrict__ stats,
                                               const float* __restrict__ gamma,
                                               const float* __restrict__ beta,
                                               unsigned short* __restrict__ g2, int n) {
    __shared__ unsigned short Ws[64 * 128];
    __shared__ float sSc[128], sSh[128];
    const int tid = threadIdx.x;
    if (tid < 128) {  // fused BN scale/shift from sums
        float inv_n = 1.f / (float)n;
        float mean = stats[tid] * inv_n;
        float var = stats[128 + tid] * inv_n - mean * mean;
        float sc = gamma[tid] * rsqrtf(var + BN_EPS);
        sSc[tid] = sc;
        sSh[tid] = fmaf(-mean, sc, beta[tid]);
    }
#pragma unroll
    for (int i = 0; i < 8; ++i) {
        int idx4 = i * 256 + tid;
        int j = idx4 >> 5;
        int k = (idx4 & 31) * 4;
        float4 v = *(const float4*)&W2[(size_t)j * 128 + k];
        ushort4 u;
        u.x = f2bf(v.x); u.y = f2bf(v.y); u.z = f2bf(v.z); u.w = f2bf(v.w);
        *(ushort2*)&Ws[wsw(j, k)] = make_ushort2(u.x, u.y);
        *(ushort2*)&Ws[wsw(j, k + 2)] = make_ushort2(u.z, u.w);
    }
    __syncthreads();
    const int wave = tid >> 6, l = tid & 63;
    const int am = l & 15;
    const int kg = l >> 4;
    const int row0 = blockIdx.x * 64 + wave * 16;
    const int grow = row0 + am;
    const unsigned short* hrow = &h1[(size_t)(grow < n ? grow : 0) * 128];
    f32x4 acc[4] = {};
#pragma unroll
    for (int k0 = 0; k0 < 128; k0 += 32) {
        const int kk = k0 + kg * 8;
        uint4 hq = *(const uint4*)&hrow[kk];
        float2 p0 = bf2x2(hq.x), p1 = bf2x2(hq.y), p2 = bf2x2(hq.z), p3 = bf2x2(hq.w);
        float hf[8] = {p0.x, p0.y, p1.x, p1.y, p2.x, p2.y, p3.x, p3.y};
        float4 sc0 = *(const float4*)&sSc[kk];
        float4 sc1 = *(const float4*)&sSc[kk + 4];
        float4 sh0 = *(const float4*)&sSh[kk];
        float4 sh1 = *(const float4*)&sSh[kk + 4];
        float scv[8] = {sc0.x, sc0.y, sc0.z, sc0.w, sc1.x, sc1.y, sc1.z, sc1.w};
        float shv[8] = {sh0.x, sh0.y, sh0.z, sh0.w, sh1.x, sh1.y, sh1.z, sh1.w};
        union { unsigned short u[8]; bf16x8 v; } af;
#pragma unroll
        for (int jj = 0; jj < 8; ++jj)
            af.u[jj] = f2bf(fmaxf(fmaf(hf[jj], scv[jj], shv[jj]), 0.f));
#pragma unroll
        for (int ct = 0; ct < 4; ++ct) {
            union { uint4 q; bf16x8 v; } bf;
            bf.q = *(const uint4*)&Ws[wsw(ct * 16 + am, kk)];
            acc[ct] = __builtin_amdgcn_mfma_f32_16x16x32_bf16(af.v, bf.v, acc[ct], 0, 0, 0);
        }
    }
#pragma unroll
    for (int r = 0; r < 4; ++r) {
        int orow = row0 + kg * 4 + r;
        if (orow < n) {
            float di = dinv[orow];
#pragma unroll
            for (int ct = 0; ct < 4; ++ct)
                g2[(size_t)orow * 64 + ct * 16 + am] = f2bf(acc[ct][r] * di);
        }
    }
}

// ---------------- pull2: out[d] = dinv[d]*(g2[d] + sum g2[src]) + b2 ----------------
__global__ __launch_bounds__(256) void k_pull2(const int* __restrict__ rowptr, const int* __restrict__ rowend,
                                               const int* __restrict__ esrc, const unsigned short* __restrict__ g,
                                               const float* __restrict__ dinv, const float* __restrict__ b2,
                                               float* __restrict__ out, int n) {
    const int wid = threadIdx.x >> 6, lane = threadIdx.x & 63;
    const int gw = blockIdx.x * 4 + wid;
    const int nw = gridDim.x * 4;
    const float bias = b2[lane];
    for (int node = gw; node < n; node += nw) {
        const int b = rowptr[node], e = rowend[node];
        float a0 = bf2f(g[(size_t)node * 64 + lane]);  // self loop
        float a1 = 0.f, a2 = 0.f, a3 = 0.f, a4 = 0.f, a5 = 0.f, a6 = 0.f, a7 = 0.f;
        int j = b;
        for (; j + 8 <= e; j += 8) {
            int s0 = esrc[j + 0], s1 = esrc[j + 1], s2 = esrc[j + 2], s3 = esrc[j + 3];
            int s4 = esrc[j + 4], s5 = esrc[j + 5], s6 = esrc[j + 6], s7 = esrc[j + 7];
            unsigned short v0 = g[(size_t)s0 * 64 + lane];
            unsigned short v1 = g[(size_t)s1 * 64 + lane];
            unsigned short v2 = g[(size_t)s2 * 64 + lane];
            unsigned short v3 = g[(size_t)s3 * 64 + lane];
            unsigned short v4 = g[(size_t)s4 * 64 + lane];
            unsigned short v5 = g[(size_t)s5 * 64 + lane];
            unsigned short v6 = g[(size_t)s6 * 64 + lane];
            unsigned short v7 = g[(size_t)s7 * 64 + lane];
            a0 += bf2f(v0); a1 += bf2f(v1); a2 += bf2f(v2); a3 += bf2f(v3);
            a4 += bf2f(v4); a5 += bf2f(v5); a6 += bf2f(v6); a7 += bf2f(v7);
        }
        for (; j < e; ++j) a0 += bf2f(g[(size_t)esrc[j] * 64 + lane]);
        float acc = ((a0 + a1) + (a2 + a3)) + ((a4 + a5) + (a6 + a7));
        __builtin_nontemporal_store(fmaf(acc, dinv[node], bias), &out[(size_t)node * 64 + lane]);
    }
}

extern "C" void kernel_launch(void* const* d_in, const int* in_sizes, int n_in,
                              void* d_out, int out_size, void* d_ws, size_t ws_size,
                              hipStream_t stream) {
    const float* x     = (const float*)d_in[0];
    const int*   ei    = (const int*)d_in[1];
    const float* W1    = (const float*)d_in[2];
    const float* b1    = (const float*)d_in[3];
    const float* gamma = (const float*)d_in[4];
    const float* beta  = (const float*)d_in[5];
    const float* W2    = (const float*)d_in[6];
    const float* b2    = (const float*)d_in[7];
    float* out = (float*)d_out;

    const int n = in_sizes[0] / 128;
    const int E = in_sizes[1] / 2;
    const int* src = ei;
    const int* dst = ei + E;
    const int NB = (n + 127) >> BSH;
    const int Np = (n + 255) & ~255;
    const int Ep = (E + 3) & ~3;

    char* ws = (char*)d_ws;
    int*   gcount = (int*)ws;                 // 1024
    int*   gstart = gcount + 1024;            // 1088 (NB+1)
    int*   cursor = gstart + 1088;            // 1024
    float* stats  = (float*)(cursor + 1024);  // 512: [0,128)sum [128,256)sumsq
    float* dinv   = stats + 512;              // Np
    int*   rowptr = (int*)(dinv + Np);        // Np
    int*   rowend = rowptr + Np;              // Np
    int*   pairs  = rowend + Np;              // Ep (packed src|dlocal<<20)
    int*   esrc   = pairs + Ep;               // Ep
    unsigned short* g1 = (unsigned short*)(esrc + Ep);   // n*128 bf16
    unsigned short* h1 = g1 + (size_t)n * 128;           // n*128 bf16
    unsigned short* g2 = g1;                             // reuse (g1 dead after pull1)

    const int gb = (n + 63) / 64;
    const int gh = (E + 8191) / 8192;
    const int gs = (E + 4095) / 4096;

    hipLaunchKernelGGL(k_zero, dim3(1), dim3(1024), 0, stream, gcount);
    hipLaunchKernelGGL(k_hist, dim3(gh), dim3(256), 0, stream, dst, gcount, E, NB);
    hipLaunchKernelGGL(k_scanb, dim3(1), dim3(1024), 0, stream, gcount, gstart, cursor, stats, NB);
    hipLaunchKernelGGL(k_scatter, dim3(gs), dim3(256), 0, stream, src, dst, cursor, pairs, E, NB);
    hipLaunchKernelGGL(k_build, dim3(NB), dim3(256), 0, stream, pairs, gstart, rowptr, rowend, dinv, esrc, n);

    hipLaunchKernelGGL(k_gemm1, dim3(gb), dim3(256), 0, stream, x, W1, dinv, g1, n);
    hipLaunchKernelGGL(k_pull1, dim3(2048), dim3(256), 0, stream, rowptr, rowend, esrc, g1, dinv, b1, h1, stats, n);

    hipLaunchKernelGGL(k_gemm2, dim3(gb), dim3(256), 0, stream, h1, W2, dinv, stats, gamma, beta, g2, n);
    hipLaunchKernelGGL(k_pull2, dim3(2048), dim3(256), 0, stream, rowptr, rowend, esrc, g2, dinv, b2, out, n);
}